// Round 1
// 436.621 us; speedup vs baseline: 1.0912x; 1.0912x over previous
//
#include <hip/hip_runtime.h>
#include <math.h>

typedef unsigned short ushort_t;
typedef __attribute__((ext_vector_type(4))) float floatx4;
typedef __attribute__((ext_vector_type(8))) short bf16x8;

#define DIMC 1152
#define NHEADS 16
#define HDIM 72

__device__ __forceinline__ ushort_t f2bf(float f) {
  unsigned u = __float_as_uint(f);
  u += 0x7FFFu + ((u >> 16) & 1u);      // round-to-nearest-even
  return (ushort_t)(u >> 16);
}
__device__ __forceinline__ float bf2f(ushort_t s) {
  return __uint_as_float(((unsigned)s) << 16);
}

__device__ __forceinline__ void gload_lds16(const ushort_t* g, ushort_t* l) {
  __builtin_amdgcn_global_load_lds(
      (const __attribute__((address_space(1))) unsigned int*)(const void*)g,
      (__attribute__((address_space(3))) unsigned int*)(void*)l, 16, 0, 0);
}

__device__ __forceinline__ bf16x8 load_bf16x8(const ushort_t* p) {
  union { bf16x8 v; uint4 u; } t;
  t.u = *(const uint4*)p;
  return t.v;
}

// ---------------------------------------------------------------------------
// fp32 -> bf16 elementwise (8 elems/thread)
// ---------------------------------------------------------------------------
__global__ void cvt_bf16_kernel(const float* __restrict__ src,
                                ushort_t* __restrict__ dst, int n8) {
  int i = blockIdx.x * 256 + threadIdx.x;
  if (i >= n8) return;
  float4 f0 = ((const float4*)src)[2 * (size_t)i];
  float4 f1 = ((const float4*)src)[2 * (size_t)i + 1];
  union { ushort_t s[8]; uint4 u; } t;
  t.s[0] = f2bf(f0.x); t.s[1] = f2bf(f0.y); t.s[2] = f2bf(f0.z); t.s[3] = f2bf(f0.w);
  t.s[4] = f2bf(f1.x); t.s[5] = f2bf(f1.y); t.s[6] = f2bf(f1.z); t.s[7] = f2bf(f1.w);
  ((uint4*)dst)[i] = t.u;
}

// ---------------------------------------------------------------------------
// W [K][N] fp32  ->  Wt [N][K] bf16   (64x64 tiles via LDS)
// ---------------------------------------------------------------------------
__global__ void transpose_w_kernel(const float* __restrict__ W,
                                   ushort_t* __restrict__ Wt, int K, int N) {
  __shared__ ushort_t tile[64 * 80];
  int k0 = blockIdx.x * 64, n0 = blockIdx.y * 64;
  int tid = threadIdx.x;
  int kl = tid >> 4, n4 = tid & 15;
  for (int rr = 0; rr < 4; rr++) {
    int k = kl + rr * 16;
    float4 f = *(const float4*)(W + (size_t)(k0 + k) * N + n0 + n4 * 4);
    tile[(n4 * 4 + 0) * 80 + k] = f2bf(f.x);
    tile[(n4 * 4 + 1) * 80 + k] = f2bf(f.y);
    tile[(n4 * 4 + 2) * 80 + k] = f2bf(f.z);
    tile[(n4 * 4 + 3) * 80 + k] = f2bf(f.w);
  }
  __syncthreads();
  int nl = tid >> 2, kq = tid & 3;
  uint4 v0 = *(const uint4*)(tile + nl * 80 + kq * 16);
  uint4 v1 = *(const uint4*)(tile + nl * 80 + kq * 16 + 8);
  *(uint4*)(Wt + (size_t)(n0 + nl) * K + k0 + kq * 16) = v0;
  *(uint4*)(Wt + (size_t)(n0 + nl) * K + k0 + kq * 16 + 8) = v1;
}

// ---------------------------------------------------------------------------
// Old 128x128 GEMM (m97 structure) — kept for the small KV projection.
// ---------------------------------------------------------------------------
template <bool OUT_F32>
__global__ __launch_bounds__(256, 3) void gemm_kernel(
    const ushort_t* __restrict__ A, const ushort_t* __restrict__ Bt,
    const float* __restrict__ bias, void* __restrict__ Cptr,
    int TM, int TN, int Ncols, int Kdim) {
  __shared__ ushort_t As[16 * 512];
  __shared__ ushort_t Bs[16 * 512];
  int lin = blockIdx.x;
  int xcd = lin & 7, slot = lin >> 3;
  int mpx = TM >> 3;
  int mt = xcd * mpx + slot / TN;
  int nt = slot % TN;
  int m0 = mt * 128, n0 = nt * 128;

  int tid = threadIdx.x;
  int wid = tid >> 6, lane = tid & 63, quad = lane >> 4, l16 = lane & 15;
  int wrow = (wid >> 1) * 64, wcol = (wid & 1) * 64;
  int crA = (wid >> 1) * 4;
  int crB = (wid & 1) * 4;

  floatx4 zero = {0.f, 0.f, 0.f, 0.f};
  floatx4 acc[4][4];
  for (int i = 0; i < 4; i++)
    for (int j = 0; j < 4; j++) acc[i][j] = zero;

  int nK = Kdim >> 6;
  for (int kt = 0; kt < nK; kt++) {
    int k0 = kt * 64;
    __syncthreads();
    for (int i = 0; i < 4; i++) {
      int c = wid * 4 + i;
      int cr = c >> 1, cks = c & 1;
      const ushort_t* ga =
          A + (size_t)(m0 + cr * 16 + l16) * Kdim + k0 + cks * 32 + quad * 8;
      gload_lds16(ga, As + c * 512);
      const ushort_t* gb =
          Bt + (size_t)(n0 + cr * 16 + l16) * Kdim + k0 + cks * 32 + quad * 8;
      gload_lds16(gb, Bs + c * 512);
    }
    __syncthreads();
    for (int ks = 0; ks < 2; ks++) {
      bf16x8 af[4], bfr[4];
      for (int rb = 0; rb < 4; rb++)
        af[rb] = *(const bf16x8*)(As + ((crA + rb) * 2 + ks) * 512 + lane * 8);
      for (int c = 0; c < 4; c++)
        bfr[c] = *(const bf16x8*)(Bs + ((crB + c) * 2 + ks) * 512 + lane * 8);
      for (int rb = 0; rb < 4; rb++)
        for (int c = 0; c < 4; c++)
          acc[rb][c] = __builtin_amdgcn_mfma_f32_16x16x32_bf16(af[rb], bfr[c], acc[rb][c], 0, 0, 0);
    }
  }

  float bv[4];
  for (int c = 0; c < 4; c++) bv[c] = bias[n0 + wcol + c * 16 + l16];
  for (int rb = 0; rb < 4; rb++)
    for (int c = 0; c < 4; c++)
      for (int r = 0; r < 4; r++) {
        int row = m0 + wrow + rb * 16 + quad * 4 + r;
        int col = n0 + wcol + c * 16 + l16;
        float v = acc[rb][c][r] + bv[c];
        if constexpr (OUT_F32)
          ((float*)Cptr)[(size_t)row * Ncols + col] = v;
        else
          ((ushort_t*)Cptr)[(size_t)row * Ncols + col] = f2bf(v);
      }
}

// ---------------------------------------------------------------------------
// 256x256 8-phase GEMM (m201 structure: T2 st_16x32 swizzle + T3/T4 counted
// vmcnt + T5 setprio). BK=64, 512 threads = 8 waves (2M x 4N), per-wave
// 128x64 output = acc[8][4]. LDS 128 KiB: [buf][mat][half][ks][128r][32c]
// bf16 slabs (row stride 64B), XOR-swizzle byte5 ^= byte9 (ushort bit4 ^=
// row bit3). Staging via global_load_lds w=16 with pre-swizzled global
// source; one 8KB slab per call (2 calls per half-tile).
// Stage stream per tile t:  ph0:(t+1)A0  ph1:(t+1)A1  ph2:(t+2)B0
// ph3:(t+2)B1 ; vmcnt(4) at end of ph3 guards tile t+1 (drains to 0 for the
// last two tiles). B-fragments register-cached in ph0 so ph2/ph3 B-staging
// into the live buffer is safe (reads completed before ph0's trailing
// barrier).
// N not multiple of 256: last N-tile overlaps (n0 = Ncols-256); overlapped
// columns are recomputed bitwise-identically, so double-writes are benign.
// Grid must be a multiple of 8 (XCD swizzle).
// ---------------------------------------------------------------------------
template <bool OUT_F32>
__global__ __launch_bounds__(512, 2) void gemm256_kernel(
    const ushort_t* __restrict__ A, const ushort_t* __restrict__ Bt,
    const float* __restrict__ bias, void* __restrict__ Cptr,
    int MT, int NTn, int Ncols, int Kdim) {
  __shared__ ushort_t S[65536];  // 128 KiB

  int lin = blockIdx.x;
  int nwg = MT * NTn;
  int cpx = nwg >> 3;                       // nwg % 8 == 0 assumed
  int wg = (lin & 7) * cpx + (lin >> 3);    // XCD-contiguous
  int mt = wg / NTn, nt = wg % NTn;
  int m0 = mt * 256;
  int n0 = nt * 256;
  if (n0 + 256 > Ncols) n0 = Ncols - 256;   // overlapped last tile

  int tid = threadIdx.x;
  int wid = tid >> 6, lane = tid & 63, quad = lane >> 4, l16 = lane & 15;
  int wr = wid >> 2, wc = wid & 3;
  const int qoff = (quad * 8) ^ ((l16 & 8) << 1);  // swizzled read col (ushorts)

  // staging source coords (per thread), pre-swizzled
  const int srow = tid >> 2;                                   // 0..127
  const int scol = ((tid & 3) * 8) ^ ((tid & 32) ? 16 : 0);    // ushorts
  const int wslot = (tid >> 6) * 512;                          // wave-uniform

  auto stageA = [&](int t, int h) {
    const ushort_t* src = A + (size_t)(m0 + h * 128 + srow) * Kdim + t * 64 + scol;
    ushort_t* dst = S + (t & 1) * 32768 + h * 8192 + wslot;
    gload_lds16(src, dst);               // ks=0 slab
    gload_lds16(src + 32, dst + 4096);   // ks=1 slab
  };
  auto stageB = [&](int t, int h) {
    const ushort_t* src = Bt + (size_t)(n0 + h * 128 + srow) * Kdim + t * 64 + scol;
    ushort_t* dst = S + (t & 1) * 32768 + 16384 + h * 8192 + wslot;
    gload_lds16(src, dst);
    gload_lds16(src + 32, dst + 4096);
  };

  floatx4 zero = {0.f, 0.f, 0.f, 0.f};
  floatx4 acc[8][4];
#pragma unroll
  for (int i = 0; i < 8; i++)
#pragma unroll
    for (int j = 0; j < 4; j++) acc[i][j] = zero;

  int NT = Kdim >> 6;

  // prologue: tile0 fully, tile1 B-halves; 3 half-tiles stay in flight
  stageA(0, 0); stageA(0, 1); stageB(0, 0); stageB(0, 1);
  stageB(1, 0); stageB(1, 1);
  asm volatile("s_waitcnt vmcnt(4)" ::: "memory");
  __builtin_amdgcn_s_barrier();

  for (int t = 0; t < NT; ++t) {
    const int ab = (t & 1) * 32768 + wr * 8192;
    const int bb = (t & 1) * 32768 + 16384 + (wc >> 1) * 8192;
    const int brow = (wc & 1) * 64;

    bf16x8 bfr[4][2];

    // ---------------- phase 0 : B all + A frags 0,1 ----------------
    bf16x8 a0[2], a1[2];
#pragma unroll
    for (int c = 0; c < 4; c++)
#pragma unroll
      for (int ks = 0; ks < 2; ks++)
        bfr[c][ks] = *(const bf16x8*)(S + bb + ks * 4096 +
                                      (brow + c * 16 + l16) * 32 + qoff);
#pragma unroll
    for (int ks = 0; ks < 2; ks++) {
      a0[ks] = *(const bf16x8*)(S + ab + ks * 4096 + (l16) * 32 + qoff);
      a1[ks] = *(const bf16x8*)(S + ab + ks * 4096 + (16 + l16) * 32 + qoff);
    }
    if (t + 1 < NT) stageA(t + 1, 0);
    __builtin_amdgcn_s_barrier();
    asm volatile("s_waitcnt lgkmcnt(0)" ::: "memory");
    __builtin_amdgcn_sched_barrier(0);
    __builtin_amdgcn_s_setprio(1);
#pragma unroll
    for (int ks = 0; ks < 2; ks++)
#pragma unroll
      for (int c = 0; c < 4; c++) {
        acc[0][c] = __builtin_amdgcn_mfma_f32_16x16x32_bf16(a0[ks], bfr[c][ks], acc[0][c], 0, 0, 0);
        acc[1][c] = __builtin_amdgcn_mfma_f32_16x16x32_bf16(a1[ks], bfr[c][ks], acc[1][c], 0, 0, 0);
      }
    __builtin_amdgcn_s_setprio(0);
    __builtin_amdgcn_s_barrier();

    // ---------------- phases 1..3 : A frags 2ph,2ph+1 ----------------
#pragma unroll
    for (int ph = 1; ph < 4; ++ph) {
      bf16x8 af[2][2];
#pragma unroll
      for (int i = 0; i < 2; i++)
#pragma unroll
        for (int ks = 0; ks < 2; ks++)
          af[i][ks] = *(const bf16x8*)(S + ab + ks * 4096 +
                                       ((ph * 2 + i) * 16 + l16) * 32 + qoff);
      if (ph == 1) {
        if (t + 1 < NT) stageA(t + 1, 1);
      } else if (ph == 2) {
        if (t + 2 < NT) stageB(t + 2, 0);
      } else {
        if (t + 2 < NT) stageB(t + 2, 1);
      }
      __builtin_amdgcn_s_barrier();
      asm volatile("s_waitcnt lgkmcnt(0)" ::: "memory");
      __builtin_amdgcn_sched_barrier(0);
      __builtin_amdgcn_s_setprio(1);
#pragma unroll
      for (int ks = 0; ks < 2; ks++)
#pragma unroll
        for (int c = 0; c < 4; c++) {
          acc[ph * 2][c] = __builtin_amdgcn_mfma_f32_16x16x32_bf16(af[0][ks], bfr[c][ks], acc[ph * 2][c], 0, 0, 0);
          acc[ph * 2 + 1][c] = __builtin_amdgcn_mfma_f32_16x16x32_bf16(af[1][ks], bfr[c][ks], acc[ph * 2 + 1][c], 0, 0, 0);
        }
      __builtin_amdgcn_s_setprio(0);
      if (ph == 3) {
        if (t < NT - 2)
          asm volatile("s_waitcnt vmcnt(4)" ::: "memory");
        else
          asm volatile("s_waitcnt vmcnt(0)" ::: "memory");
      }
      __builtin_amdgcn_s_barrier();
    }
  }

  // epilogue
  float bv[4];
#pragma unroll
  for (int c = 0; c < 4; c++) bv[c] = bias[n0 + wc * 64 + c * 16 + l16];
#pragma unroll
  for (int mf = 0; mf < 8; mf++)
#pragma unroll
    for (int c = 0; c < 4; c++)
#pragma unroll
      for (int r = 0; r < 4; r++) {
        int row = m0 + wr * 128 + mf * 16 + quad * 4 + r;
        int col = n0 + wc * 64 + c * 16 + l16;
        float v = acc[mf][c][r] + bv[c];
        if constexpr (OUT_F32)
          ((float*)Cptr)[(size_t)row * Ncols + col] = v;
        else
          ((ushort_t*)Cptr)[(size_t)row * Ncols + col] = f2bf(v);
      }
}

// ---------------------------------------------------------------------------
// In-place per-head RMSNorm on bf16 (one wave per (row, head); 72 elems).
// Used only for K (Q norm fused into attention).
// ---------------------------------------------------------------------------
__global__ void rmsnorm_heads_kernel(ushort_t* __restrict__ p,
                                     const float* __restrict__ w,
                                     int rowstride) {
  int gw = blockIdx.x * 4 + (threadIdx.x >> 6);
  int lane = threadIdx.x & 63;
  int row = gw >> 4, h = gw & 15;
  ushort_t* base = p + (size_t)row * rowstride + h * HDIM;
  float v0 = bf2f(base[lane]);
  float v1 = (lane < 8) ? bf2f(base[64 + lane]) : 0.f;
  float ss = v0 * v0 + v1 * v1;
  for (int off = 1; off < 64; off <<= 1) ss += __shfl_xor(ss, off);
  float inv = rsqrtf(ss / 72.0f + 1e-6f);
  base[lane] = f2bf(v0 * inv * w[lane]);
  if (lane < 8) base[64 + lane] = f2bf(v1 * inv * w[64 + lane]);
}

// ---------------------------------------------------------------------------
// V [b,m,pair1,h,d] -> vT [b,h,d(80),m(512)]; d==72 row = ONES (gives P
// row-sums for free via the PV MFMA), d in (72,80) zeros.
// ---------------------------------------------------------------------------
__global__ void vtrans_kernel(const ushort_t* __restrict__ kv16,
                              ushort_t* __restrict__ vT) {
  int gw = blockIdx.x * 4 + (threadIdx.x >> 6);
  int lane = threadIdx.x & 63;
  int d = gw % 80;
  int bh = gw / 80;
  int b = bh >> 4, h = bh & 15;
  ushort_t* dst = vT + (size_t)gw * 512;
  if (d < HDIM) {
    const ushort_t* src = kv16 + (size_t)b * 512 * 2304 + DIMC + h * HDIM + d;
    for (int m = lane; m < 512; m += 64) dst[m] = src[(size_t)m * 2304];
  } else {
    ushort_t fill = (d == HDIM) ? (ushort_t)0x3F80 : (ushort_t)0;  // 1.0 or 0
    for (int m = lane; m < 512; m += 64) dst[m] = fill;
  }
}

// ---------------------------------------------------------------------------
// Flash cross-attention, fused Q-RMSNorm, no-max softmax (post-RMSNorm
// |s*scale| <= sqrt(72) ~ 8.5, exp2-safe in fp32). K/V tiles staged
// cooperatively into LDS via global_load_lds width 16 in MFMA-fragment
// chunk order (m97 structure): 22 chunks x 1KB, waves stage 6/6/5/5,
// 2 barriers per tile; all LDS accesses are conflict-free b128.
// P row-sums via ones-row (d=72) of vT through the PV MFMA.
// Ps is wave-private, XOR-swizzled.
// ---------------------------------------------------------------------------
__global__ __launch_bounds__(256, 4) void attn_kernel(
    const ushort_t* __restrict__ q16, const ushort_t* __restrict__ kv16,
    const ushort_t* __restrict__ vT, const int* __restrict__ seqlens,
    const float* __restrict__ qn_w, ushort_t* __restrict__ att) {
  __shared__ ushort_t KV[22 * 512];     // K chunks 0..11 (c*3+ks), V 12..21 (12+nf*2+ks)
  __shared__ ushort_t Ps[4][32 * 64];   // per-wave [row 32][m 64] swizzled
  int b = blockIdx.z, h = blockIdx.y, n0 = blockIdx.x * 128;
  int tid = threadIdx.x, wid = tid >> 6, lane = tid & 63;
  int quad = lane >> 4, l16 = lane & 15;
  int seqlen = seqlens[b];
  // 1/sqrt(72) * log2(e) folded into Q so that P = exp2(S)
  const float qscale = 0.11785113019775793f * 1.44269504088896f;

  ushort_t* Pw = &Ps[wid][0];

  // --- Q fragments + fused RMSNorm (qn_w and qscale folded in) ---
  bf16x8 qf[2][3];
  float ssq[2] = {0.f, 0.f};
  for (int rb = 0; rb < 2; rb++)
    for (int ks = 0; ks < 3; ks++) {
      if (ks == 2 && quad > 0) {
        qf[rb][ks] = (bf16x8){0, 0, 0, 0, 0, 0, 0, 0};
      } else {
        size_t off = ((size_t)(b * 4096 + n0 + wid * 32 + rb * 16 + l16)) * DIMC +
                     h * HDIM + ks * 32 + quad * 8;
        qf[rb][ks] = load_bf16x8(q16 + off);
        union { bf16x8 v; ushort_t s[8]; } e;
        e.v = qf[rb][ks];
        for (int j = 0; j < 8; j++) {
          float x = bf2f(e.s[j]);
          ssq[rb] += x * x;
        }
      }
    }
  for (int rb = 0; rb < 2; rb++) {
    ssq[rb] += __shfl_xor(ssq[rb], 16);
    ssq[rb] += __shfl_xor(ssq[rb], 32);
  }
  for (int rb = 0; rb < 2; rb++) {
    float inv = rsqrtf(ssq[rb] / 72.0f + 1e-6f) * qscale;
    for (int ks = 0; ks < 3; ks++) {
      if (ks == 2 && quad > 0) continue;
      float4 w0 = *(const float4*)(qn_w + ks * 32 + quad * 8);
      float4 w1 = *(const float4*)(qn_w + ks * 32 + quad * 8 + 4);
      union { bf16x8 v; ushort_t s[8]; } e;
      e.v = qf[rb][ks];
      e.s[0] = f2bf(bf2f(e.s[0]) * inv * w0.x);
      e.s[1] = f2bf(bf2f(e.s[1]) * inv * w0.y);
      e.s[2] = f2bf(bf2f(e.s[2]) * inv * w0.z);
      e.s[3] = f2bf(bf2f(e.s[3]) * inv * w0.w);
      e.s[4] = f2bf(bf2f(e.s[4]) * inv * w1.x);
      e.s[5] = f2bf(bf2f(e.s[5]) * inv * w1.y);
      e.s[6] = f2bf(bf2f(e.s[6]) * inv * w1.z);
      e.s[7] = f2bf(bf2f(e.s[7]) * inv * w1.w);
      qf[rb][ks] = e.v;
    }
  }

  floatx4 zero = {0.f, 0.f, 0.f, 0.f};
  floatx4 of[2][5];
  for (int rb = 0; rb < 2; rb++)
    for (int nf = 0; nf < 5; nf++) of[rb][nf] = zero;

  const size_t kvrow = (size_t)b * 512;
  const size_t vbase = (size_t)((b * 16 + h) * 80) * 512;

  int ntiles = (seqlen + 63) >> 6;
  for (int mt = 0; mt < ntiles; mt++) {
    int m0 = mt * 64;

    __syncthreads();   // previous tile's LDS reads done
    // cooperative staging: 22 chunks, wave w takes id = w, w+4, ...
    for (int id = wid; id < 22; id += 4) {
      const ushort_t* src;
      if (id < 12) {
        int c = (id * 11) >> 5;     // floor(id/3) for id<12: 0..3
        int ks = id - c * 3;
        src = kv16 + (size_t)(kvrow + m0 + c * 16 + l16) * 2304 + h * HDIM +
              ks * 32 + quad * 8;
      } else {
        int v = id - 12;
        int nf = v >> 1, ks = v & 1;
        src = vT + (vbase + (size_t)(nf * 16 + l16) * 512) + m0 + ks * 32 + quad * 8;
      }
      gload_lds16(src, KV + id * 512);
    }
    __syncthreads();   // staging complete

    // S = Q K^T from LDS K-frags (d >= 72 garbage x Q-zeros)
    floatx4 sf[2][4];
    for (int rb = 0; rb < 2; rb++)
      for (int c = 0; c < 4; c++) sf[rb][c] = zero;
    for (int c = 0; c < 4; c++)
      for (int ks = 0; ks < 3; ks++) {
        bf16x8 kf = *(const bf16x8*)(KV + (c * 3 + ks) * 512 + lane * 8);
        for (int rb = 0; rb < 2; rb++)
          sf[rb][c] = __builtin_amdgcn_mfma_f32_16x16x32_bf16(qf[rb][ks], kf, sf[rb][c], 0, 0, 0);
      }

    // P = exp2(S) masked; write to wave-private swizzled LDS
    for (int rb = 0; rb < 2; rb++)
      for (int c = 0; c < 4; c++) {
        bool valid = (m0 + c * 16 + l16) < seqlen;
        int col = (c * 16 + l16) ^ (quad * 16);
        int rowb = rb * 16 + quad * 4;
        for (int r = 0; r < 4; r++) {
          float pp = valid ? __builtin_amdgcn_exp2f(sf[rb][c][r]) : 0.f;
          Pw[(rowb + r) * 64 + col] = f2bf(pp);
        }
      }

    // O += P V from LDS V-frags (nf=4 includes ones-row d=72)
    for (int ks = 0; ks < 2; ks++) {
      bf16x8 pf[2];
      int g = ((ks * 2 + (quad >> 1)) * 16 + (quad & 1) * 8) ^ (((l16 >> 2) & 3) * 16);
      for (int rb = 0; rb < 2; rb++)
        pf[rb] = *(const bf16x8*)(Pw + (rb * 16 + l16) * 64 + g);
      for (int nf = 0; nf < 5; nf++) {
        bf16x8 vf = *(const bf16x8*)(KV + (12 + nf * 2 + ks) * 512 + lane * 8);
        for (int rb = 0; rb < 2; rb++)
          of[rb][nf] = __builtin_amdgcn_mfma_f32_16x16x32_bf16(pf[rb], vf, of[rb][nf], 0, 0, 0);
      }
    }
  }

  // normalize by the ones-column sums (d=72 -> nf=4, l16=8) and store
  for (int rb = 0; rb < 2; rb++) {
    float invl[4];
    for (int r = 0; r < 4; r++) {
      float lsum = __shfl(of[rb][4][r], (lane & 48) | 8);
      invl[r] = 1.0f / lsum;
    }
    for (int nf = 0; nf < 5; nf++) {
      int d = nf * 16 + l16;
      if (d < HDIM) {
        for (int r = 0; r < 4; r++) {
          size_t o = ((size_t)(b * 4096 + n0 + wid * 32 + rb * 16 + quad * 4 + r)) * DIMC +
                     h * HDIM + d;
          att[o] = f2bf(of[rb][nf][r] * invl[r]);
        }
      }
    }
  }
}

// ---------------------------------------------------------------------------
extern "C" void kernel_launch(void* const* d_in, const int* in_sizes, int n_in,
                              void* d_out, int out_size, void* d_ws, size_t ws_size,
                              hipStream_t stream) {
  const float* x      = (const float*)d_in[0];
  const float* cond   = (const float*)d_in[1];
  const int*   seqlen = (const int*)d_in[2];
  const float* q_w    = (const float*)d_in[3];
  const float* q_b    = (const float*)d_in[4];
  const float* kv_w   = (const float*)d_in[5];
  const float* kv_b   = (const float*)d_in[6];
  const float* proj_w = (const float*)d_in[7];
  const float* proj_b = (const float*)d_in[8];
  const float* qn_w   = (const float*)d_in[9];
  const float* kn_w   = (const float*)d_in[10];
  float* out = (float*)d_out;

  char* ws = (char*)d_ws;
  size_t o = 0;
  ushort_t* qwT    = (ushort_t*)(ws + o); o += (size_t)1152 * 1152 * 2;
  ushort_t* kvwT   = (ushort_t*)(ws + o); o += (size_t)2304 * 1152 * 2;
  ushort_t* pwT    = (ushort_t*)(ws + o); o += (size_t)1152 * 1152 * 2;
  ushort_t* q16    = (ushort_t*)(ws + o); o += (size_t)16384 * 1152 * 2;
  ushort_t* kv16   = (ushort_t*)(ws + o); o += (size_t)2048 * 2304 * 2;
  ushort_t* vT     = (ushort_t*)(ws + o); o += (size_t)64 * 80 * 512 * 2;
  ushort_t* att    = (ushort_t*)(ws + o); o += (size_t)16384 * 1152 * 2;
  ushort_t* x16    = (ushort_t*)(ws + o); o += (size_t)16384 * 1152 * 2;
  ushort_t* cond16 = (ushort_t*)(ws + o); o += (size_t)2048 * 1152 * 2;

  dim3 blk(256);
  dim3 blk512(512);

  // 0) activations fp32 -> bf16
  cvt_bf16_kernel<<<dim3((16384 * 1152 / 8 + 255) / 256), blk, 0, stream>>>(
      x, x16, 16384 * 1152 / 8);
  cvt_bf16_kernel<<<dim3((2048 * 1152 / 8 + 255) / 256), blk, 0, stream>>>(
      cond, cond16, 2048 * 1152 / 8);

  // 1) weight convert+transpose to bf16 [N][K]
  transpose_w_kernel<<<dim3(1152 / 64, 1152 / 64), blk, 0, stream>>>(q_w, qwT, 1152, 1152);
  transpose_w_kernel<<<dim3(1152 / 64, 2304 / 64), blk, 0, stream>>>(kv_w, kvwT, 1152, 2304);
  transpose_w_kernel<<<dim3(1152 / 64, 1152 / 64), blk, 0, stream>>>(proj_w, pwT, 1152, 1152);

  // 2) Q = x @ q_w + q_b  (bf16 out)  — 256x256 8-phase, 64x5 tiles
  gemm256_kernel<false><<<dim3(64 * 5), blk512, 0, stream>>>(
      x16, qwT, q_b, q16, 64, 5, 1152, 1152);
  // 3) KV = cond @ kv_w + kv_b  (bf16 out) — small, keep 128x128 kernel
  gemm_kernel<false><<<dim3(16 * 18), blk, 0, stream>>>(
      cond16, kvwT, kv_b, kv16, 16, 18, 2304, 1152);

  // 4) RMSNorm k in place (pair-0 cols of kv16); q norm fused into attention
  rmsnorm_heads_kernel<<<dim3(2048 * 16 / 4), blk, 0, stream>>>(kv16, kn_w, 2304);

  // 5) V -> [b,h,d(80),m] with ones-row at d=72
  vtrans_kernel<<<dim3(64 * 80 / 4), blk, 0, stream>>>(kv16, vT);

  // 6) attention (fused Q-RMSNorm, no-max softmax, m97-style staging)
  attn_kernel<<<dim3(32, 16, 4), blk, 0, stream>>>(q16, kv16, vT, seqlen, qn_w, att);

  // 7) out = att @ proj_w + proj_b  (fp32 out) — 256x256 8-phase
  gemm256_kernel<true><<<dim3(64 * 5), blk512, 0, stream>>>(
      att, pwT, proj_b, out, 64, 5, 1152, 1152);
}

// Round 2
// 385.341 us; speedup vs baseline: 1.2364x; 1.1331x over previous
//
#include <hip/hip_runtime.h>
#include <math.h>

typedef unsigned short ushort_t;
typedef __attribute__((ext_vector_type(4))) float floatx4;
typedef __attribute__((ext_vector_type(8))) short bf16x8;

#define DIMC 1152
#define NHEADS 16
#define HDIM 72

__device__ __forceinline__ ushort_t f2bf(float f) {
  unsigned u = __float_as_uint(f);
  u += 0x7FFFu + ((u >> 16) & 1u);      // round-to-nearest-even
  return (ushort_t)(u >> 16);
}
__device__ __forceinline__ float bf2f(ushort_t s) {
  return __uint_as_float(((unsigned)s) << 16);
}

__device__ __forceinline__ void gload_lds16(const ushort_t* g, ushort_t* l) {
  __builtin_amdgcn_global_load_lds(
      (const __attribute__((address_space(1))) unsigned int*)(const void*)g,
      (__attribute__((address_space(3))) unsigned int*)(void*)l, 16, 0, 0);
}

__device__ __forceinline__ bf16x8 load_bf16x8(const ushort_t* p) {
  union { bf16x8 v; uint4 u; } t;
  t.u = *(const uint4*)p;
  return t.v;
}

// ---------------------------------------------------------------------------
// fp32 -> bf16 elementwise (8 elems/thread)
// ---------------------------------------------------------------------------
__global__ void cvt_bf16_kernel(const float* __restrict__ src,
                                ushort_t* __restrict__ dst, int n8) {
  int i = blockIdx.x * 256 + threadIdx.x;
  if (i >= n8) return;
  float4 f0 = ((const float4*)src)[2 * (size_t)i];
  float4 f1 = ((const float4*)src)[2 * (size_t)i + 1];
  union { ushort_t s[8]; uint4 u; } t;
  t.s[0] = f2bf(f0.x); t.s[1] = f2bf(f0.y); t.s[2] = f2bf(f0.z); t.s[3] = f2bf(f0.w);
  t.s[4] = f2bf(f1.x); t.s[5] = f2bf(f1.y); t.s[6] = f2bf(f1.z); t.s[7] = f2bf(f1.w);
  ((uint4*)dst)[i] = t.u;
}

// ---------------------------------------------------------------------------
// W [K][N] fp32  ->  Wt [N][K] bf16   (64x64 tiles via LDS)
// ---------------------------------------------------------------------------
__global__ void transpose_w_kernel(const float* __restrict__ W,
                                   ushort_t* __restrict__ Wt, int K, int N) {
  __shared__ ushort_t tile[64 * 80];
  int k0 = blockIdx.x * 64, n0 = blockIdx.y * 64;
  int tid = threadIdx.x;
  int kl = tid >> 4, n4 = tid & 15;
  for (int rr = 0; rr < 4; rr++) {
    int k = kl + rr * 16;
    float4 f = *(const float4*)(W + (size_t)(k0 + k) * N + n0 + n4 * 4);
    tile[(n4 * 4 + 0) * 80 + k] = f2bf(f.x);
    tile[(n4 * 4 + 1) * 80 + k] = f2bf(f.y);
    tile[(n4 * 4 + 2) * 80 + k] = f2bf(f.z);
    tile[(n4 * 4 + 3) * 80 + k] = f2bf(f.w);
  }
  __syncthreads();
  int nl = tid >> 2, kq = tid & 3;
  uint4 v0 = *(const uint4*)(tile + nl * 80 + kq * 16);
  uint4 v1 = *(const uint4*)(tile + nl * 80 + kq * 16 + 8);
  *(uint4*)(Wt + (size_t)(n0 + nl) * K + k0 + kq * 16) = v0;
  *(uint4*)(Wt + (size_t)(n0 + nl) * K + k0 + kq * 16 + 8) = v1;
}

// ---------------------------------------------------------------------------
// 128x128 fine-grained 2-phase GEMM, BK=32, 256 threads (4 waves 2x2,
// per-wave 64x64 = acc[4][4] -> 64 AGPR). LDS 32 KiB = 2buf x (A 8K + B 8K)
// -> 4 blocks/CU co-resident (the latency-hiding mechanism: cross-block
// wave overlap fills barrier/fill/drain bubbles of the short-K loop).
// Same st_16x32-style XOR swizzle as before (src pre-swizzled for
// global_load_lds linear dst; reads apply the same XOR): conflict-free.
// Phase schedule per K-tile t (2 phases, counted vmcnt):
//   ph0: ds_read B(all 4) + A f0,f1 ; issue stage A(t+1) ; bar ; lgkm0 ;
//        8 MFMA ; bar
//   ph1: ds_read A f2,f3 ; issue stage B(t+2) ; bar ; lgkm0 ; 8 MFMA ;
//        vmcnt(2) [keeps B(t+2) in flight] ; bar
// B(t+2) lands in the live buffer but B is only read in ph0 (register
// cached), and the stage is issued after ph0's trailing barrier -> safe.
// Two independent problem segments routed by block id (merges the Q and
// KV projections into one dispatch for packing). Grid must be %8 == 0.
// ---------------------------------------------------------------------------
template <bool OUT_F32>
__global__ __launch_bounds__(256, 4) void gemm128_kernel(
    const ushort_t* __restrict__ A0, const ushort_t* __restrict__ Bt0,
    const float* __restrict__ bias0, void* __restrict__ C0,
    int NTn0, int Ncols0,
    const ushort_t* __restrict__ A1, const ushort_t* __restrict__ Bt1,
    const float* __restrict__ bias1, void* __restrict__ C1,
    int NTn1, int Ncols1,
    int nblk0, int Kdim) {
  __shared__ ushort_t S[16384];  // 32 KiB: buf*8192 + {A:0, B:4096}

  int lin = blockIdx.x;
  int cpx = gridDim.x >> 3;
  int wg = (lin & 7) * cpx + (lin >> 3);   // XCD-contiguous chunks

  const ushort_t* Aseg; const ushort_t* Bseg;
  const float* bias; void* Cptr; int NTn, Ncols;
  if (wg < nblk0) {
    Aseg = A0; Bseg = Bt0; bias = bias0; Cptr = C0; NTn = NTn0; Ncols = Ncols0;
  } else {
    wg -= nblk0;
    Aseg = A1; Bseg = Bt1; bias = bias1; Cptr = C1; NTn = NTn1; Ncols = Ncols1;
  }
  int mt = wg / NTn, nt = wg % NTn;
  int m0 = mt * 128, n0 = nt * 128;

  int tid = threadIdx.x;
  int wid = tid >> 6, lane = tid & 63, quad = lane >> 4, l16 = lane & 15;
  int wr = wid >> 1, wc = wid & 1;
  const int qoff = (quad * 8) ^ ((l16 & 8) << 1);  // swizzled read col (ushorts)

  // staging source coords (per thread), pre-swizzled; one call = 64 rows x 32k
  const int srow = tid >> 2;                                   // 0..63
  const int scol = ((tid & 3) * 8) ^ ((tid & 32) ? 16 : 0);    // ushorts
  const ushort_t* Abase = Aseg + (size_t)m0 * Kdim;
  const ushort_t* Bbase = Bseg + (size_t)n0 * Kdim;

  auto stageA = [&](int t) {
    const ushort_t* src = Abase + (size_t)srow * Kdim + t * 32 + scol;
    ushort_t* dst = S + (t & 1) * 8192 + (tid >> 6) * 512;
    gload_lds16(src, dst);                          // rows 0..63
    gload_lds16(src + (size_t)64 * Kdim, dst + 2048);  // rows 64..127
  };
  auto stageB = [&](int t) {
    const ushort_t* src = Bbase + (size_t)srow * Kdim + t * 32 + scol;
    ushort_t* dst = S + (t & 1) * 8192 + 4096 + (tid >> 6) * 512;
    gload_lds16(src, dst);
    gload_lds16(src + (size_t)64 * Kdim, dst + 2048);
  };

  floatx4 zero = {0.f, 0.f, 0.f, 0.f};
  floatx4 acc[4][4];
#pragma unroll
  for (int i = 0; i < 4; i++)
#pragma unroll
    for (int j = 0; j < 4; j++) acc[i][j] = zero;

  int NT = Kdim >> 5;   // K-tiles of 32

  // prologue: tile0 A+B, tile1 B; keep B(1) (2 loads) in flight
  stageA(0); stageB(0); stageB(1);
  asm volatile("s_waitcnt vmcnt(2)" ::: "memory");
  __builtin_amdgcn_s_barrier();

  for (int t = 0; t < NT; ++t) {
    const int base = (t & 1) * 8192;
    const int arow = base + (wr * 64 + l16) * 32 + qoff;
    const int brow = base + 4096 + (wc * 64 + l16) * 32 + qoff;

    // ---------------- phase 0 : B all + A frags 0,1 ----------------
    bf16x8 bfr[4], a01[2];
#pragma unroll
    for (int c = 0; c < 4; c++)
      bfr[c] = *(const bf16x8*)(S + brow + c * 512);
    a01[0] = *(const bf16x8*)(S + arow);
    a01[1] = *(const bf16x8*)(S + arow + 512);
    if (t + 1 < NT) stageA(t + 1);
    __builtin_amdgcn_s_barrier();
    asm volatile("s_waitcnt lgkmcnt(0)" ::: "memory");
    __builtin_amdgcn_sched_barrier(0);
    __builtin_amdgcn_s_setprio(1);
#pragma unroll
    for (int c = 0; c < 4; c++) {
      acc[0][c] = __builtin_amdgcn_mfma_f32_16x16x32_bf16(a01[0], bfr[c], acc[0][c], 0, 0, 0);
      acc[1][c] = __builtin_amdgcn_mfma_f32_16x16x32_bf16(a01[1], bfr[c], acc[1][c], 0, 0, 0);
    }
    __builtin_amdgcn_s_setprio(0);
    __builtin_amdgcn_s_barrier();

    // ---------------- phase 1 : A frags 2,3 ----------------
    bf16x8 a23[2];
    a23[0] = *(const bf16x8*)(S + arow + 1024);
    a23[1] = *(const bf16x8*)(S + arow + 1536);
    if (t + 2 < NT) stageB(t + 2);
    __builtin_amdgcn_s_barrier();
    asm volatile("s_waitcnt lgkmcnt(0)" ::: "memory");
    __builtin_amdgcn_sched_barrier(0);
    __builtin_amdgcn_s_setprio(1);
#pragma unroll
    for (int c = 0; c < 4; c++) {
      acc[2][c] = __builtin_amdgcn_mfma_f32_16x16x32_bf16(a23[0], bfr[c], acc[2][c], 0, 0, 0);
      acc[3][c] = __builtin_amdgcn_mfma_f32_16x16x32_bf16(a23[1], bfr[c], acc[3][c], 0, 0, 0);
    }
    __builtin_amdgcn_s_setprio(0);
    if (t < NT - 2)
      asm volatile("s_waitcnt vmcnt(2)" ::: "memory");
    else
      asm volatile("s_waitcnt vmcnt(0)" ::: "memory");
    __builtin_amdgcn_s_barrier();
  }

  // epilogue
  float bv[4];
#pragma unroll
  for (int c = 0; c < 4; c++) bv[c] = bias[n0 + wc * 64 + c * 16 + l16];
#pragma unroll
  for (int mf = 0; mf < 4; mf++)
#pragma unroll
    for (int c = 0; c < 4; c++)
#pragma unroll
      for (int r = 0; r < 4; r++) {
        int row = m0 + wr * 64 + mf * 16 + quad * 4 + r;
        int col = n0 + wc * 64 + c * 16 + l16;
        float v = acc[mf][c][r] + bv[c];
        if constexpr (OUT_F32)
          ((float*)Cptr)[(size_t)row * Ncols + col] = v;
        else
          ((ushort_t*)Cptr)[(size_t)row * Ncols + col] = f2bf(v);
      }
}

// ---------------------------------------------------------------------------
// In-place per-head RMSNorm on bf16 (one wave per (row, head); 72 elems).
// Used only for K (Q norm fused into attention).
// ---------------------------------------------------------------------------
__global__ void rmsnorm_heads_kernel(ushort_t* __restrict__ p,
                                     const float* __restrict__ w,
                                     int rowstride) {
  int gw = blockIdx.x * 4 + (threadIdx.x >> 6);
  int lane = threadIdx.x & 63;
  int row = gw >> 4, h = gw & 15;
  ushort_t* base = p + (size_t)row * rowstride + h * HDIM;
  float v0 = bf2f(base[lane]);
  float v1 = (lane < 8) ? bf2f(base[64 + lane]) : 0.f;
  float ss = v0 * v0 + v1 * v1;
  for (int off = 1; off < 64; off <<= 1) ss += __shfl_xor(ss, off);
  float inv = rsqrtf(ss / 72.0f + 1e-6f);
  base[lane] = f2bf(v0 * inv * w[lane]);
  if (lane < 8) base[64 + lane] = f2bf(v1 * inv * w[64 + lane]);
}

// ---------------------------------------------------------------------------
// V [b,m,pair1,h,d] -> vT [b,h,d(80),m(512)]; d==72 row = ONES (gives P
// row-sums for free via the PV MFMA), d in (72,80) zeros.
// ---------------------------------------------------------------------------
__global__ void vtrans_kernel(const ushort_t* __restrict__ kv16,
                              ushort_t* __restrict__ vT) {
  int gw = blockIdx.x * 4 + (threadIdx.x >> 6);
  int lane = threadIdx.x & 63;
  int d = gw % 80;
  int bh = gw / 80;
  int b = bh >> 4, h = bh & 15;
  ushort_t* dst = vT + (size_t)gw * 512;
  if (d < HDIM) {
    const ushort_t* src = kv16 + (size_t)b * 512 * 2304 + DIMC + h * HDIM + d;
    for (int m = lane; m < 512; m += 64) dst[m] = src[(size_t)m * 2304];
  } else {
    ushort_t fill = (d == HDIM) ? (ushort_t)0x3F80 : (ushort_t)0;  // 1.0 or 0
    for (int m = lane; m < 512; m += 64) dst[m] = fill;
  }
}

// ---------------------------------------------------------------------------
// Flash cross-attention, fused Q-RMSNorm, no-max softmax (post-RMSNorm
// |s*scale| <= sqrt(72) ~ 8.5, exp2-safe in fp32). K/V tiles staged
// cooperatively into LDS via global_load_lds width 16 in MFMA-fragment
// chunk order: 22 chunks x 1KB, waves stage 6/6/5/5, 2 barriers per tile;
// all LDS accesses are conflict-free b128.
// P row-sums via ones-row (d=72) of vT through the PV MFMA.
// Ps is wave-private, XOR-swizzled.
// ---------------------------------------------------------------------------
__global__ __launch_bounds__(256, 4) void attn_kernel(
    const ushort_t* __restrict__ q16, const ushort_t* __restrict__ kv16,
    const ushort_t* __restrict__ vT, const int* __restrict__ seqlens,
    const float* __restrict__ qn_w, ushort_t* __restrict__ att) {
  __shared__ ushort_t KV[22 * 512];     // K chunks 0..11 (c*3+ks), V 12..21 (12+nf*2+ks)
  __shared__ ushort_t Ps[4][32 * 64];   // per-wave [row 32][m 64] swizzled
  int b = blockIdx.z, h = blockIdx.y, n0 = blockIdx.x * 128;
  int tid = threadIdx.x, wid = tid >> 6, lane = tid & 63;
  int quad = lane >> 4, l16 = lane & 15;
  int seqlen = seqlens[b];
  // 1/sqrt(72) * log2(e) folded into Q so that P = exp2(S)
  const float qscale = 0.11785113019775793f * 1.44269504088896f;

  ushort_t* Pw = &Ps[wid][0];

  // --- Q fragments + fused RMSNorm (qn_w and qscale folded in) ---
  bf16x8 qf[2][3];
  float ssq[2] = {0.f, 0.f};
  for (int rb = 0; rb < 2; rb++)
    for (int ks = 0; ks < 3; ks++) {
      if (ks == 2 && quad > 0) {
        qf[rb][ks] = (bf16x8){0, 0, 0, 0, 0, 0, 0, 0};
      } else {
        size_t off = ((size_t)(b * 4096 + n0 + wid * 32 + rb * 16 + l16)) * DIMC +
                     h * HDIM + ks * 32 + quad * 8;
        qf[rb][ks] = load_bf16x8(q16 + off);
        union { bf16x8 v; ushort_t s[8]; } e;
        e.v = qf[rb][ks];
        for (int j = 0; j < 8; j++) {
          float x = bf2f(e.s[j]);
          ssq[rb] += x * x;
        }
      }
    }
  for (int rb = 0; rb < 2; rb++) {
    ssq[rb] += __shfl_xor(ssq[rb], 16);
    ssq[rb] += __shfl_xor(ssq[rb], 32);
  }
  for (int rb = 0; rb < 2; rb++) {
    float inv = rsqrtf(ssq[rb] / 72.0f + 1e-6f) * qscale;
    for (int ks = 0; ks < 3; ks++) {
      if (ks == 2 && quad > 0) continue;
      float4 w0 = *(const float4*)(qn_w + ks * 32 + quad * 8);
      float4 w1 = *(const float4*)(qn_w + ks * 32 + quad * 8 + 4);
      union { bf16x8 v; ushort_t s[8]; } e;
      e.v = qf[rb][ks];
      e.s[0] = f2bf(bf2f(e.s[0]) * inv * w0.x);
      e.s[1] = f2bf(bf2f(e.s[1]) * inv * w0.y);
      e.s[2] = f2bf(bf2f(e.s[2]) * inv * w0.z);
      e.s[3] = f2bf(bf2f(e.s[3]) * inv * w0.w);
      e.s[4] = f2bf(bf2f(e.s[4]) * inv * w1.x);
      e.s[5] = f2bf(bf2f(e.s[5]) * inv * w1.y);
      e.s[6] = f2bf(bf2f(e.s[6]) * inv * w1.z);
      e.s[7] = f2bf(bf2f(e.s[7]) * inv * w1.w);
      qf[rb][ks] = e.v;
    }
  }

  floatx4 zero = {0.f, 0.f, 0.f, 0.f};
  floatx4 of[2][5];
  for (int rb = 0; rb < 2; rb++)
    for (int nf = 0; nf < 5; nf++) of[rb][nf] = zero;

  const size_t kvrow = (size_t)b * 512;
  const size_t vbase = (size_t)((b * 16 + h) * 80) * 512;

  int ntiles = (seqlen + 63) >> 6;
  for (int mt = 0; mt < ntiles; mt++) {
    int m0 = mt * 64;

    __syncthreads();   // previous tile's LDS reads done
    // cooperative staging: 22 chunks, wave w takes id = w, w+4, ...
    for (int id = wid; id < 22; id += 4) {
      const ushort_t* src;
      if (id < 12) {
        int c = (id * 11) >> 5;     // floor(id/3) for id<12: 0..3
        int ks = id - c * 3;
        src = kv16 + (size_t)(kvrow + m0 + c * 16 + l16) * 2304 + h * HDIM +
              ks * 32 + quad * 8;
      } else {
        int v = id - 12;
        int nf = v >> 1, ks = v & 1;
        src = vT + (vbase + (size_t)(nf * 16 + l16) * 512) + m0 + ks * 32 + quad * 8;
      }
      gload_lds16(src, KV + id * 512);
    }
    __syncthreads();   // staging complete

    // S = Q K^T from LDS K-frags (d >= 72 garbage x Q-zeros)
    floatx4 sf[2][4];
    for (int rb = 0; rb < 2; rb++)
      for (int c = 0; c < 4; c++) sf[rb][c] = zero;
    for (int c = 0; c < 4; c++)
      for (int ks = 0; ks < 3; ks++) {
        bf16x8 kf = *(const bf16x8*)(KV + (c * 3 + ks) * 512 + lane * 8);
        for (int rb = 0; rb < 2; rb++)
          sf[rb][c] = __builtin_amdgcn_mfma_f32_16x16x32_bf16(qf[rb][ks], kf, sf[rb][c], 0, 0, 0);
      }

    // P = exp2(S) masked; write to wave-private swizzled LDS
    for (int rb = 0; rb < 2; rb++)
      for (int c = 0; c < 4; c++) {
        bool valid = (m0 + c * 16 + l16) < seqlen;
        int col = (c * 16 + l16) ^ (quad * 16);
        int rowb = rb * 16 + quad * 4;
        for (int r = 0; r < 4; r++) {
          float pp = valid ? __builtin_amdgcn_exp2f(sf[rb][c][r]) : 0.f;
          Pw[(rowb + r) * 64 + col] = f2bf(pp);
        }
      }

    // O += P V from LDS V-frags (nf=4 includes ones-row d=72)
    for (int ks = 0; ks < 2; ks++) {
      bf16x8 pf[2];
      int g = ((ks * 2 + (quad >> 1)) * 16 + (quad & 1) * 8) ^ (((l16 >> 2) & 3) * 16);
      for (int rb = 0; rb < 2; rb++)
        pf[rb] = *(const bf16x8*)(Pw + (rb * 16 + l16) * 64 + g);
      for (int nf = 0; nf < 5; nf++) {
        bf16x8 vf = *(const bf16x8*)(KV + (12 + nf * 2 + ks) * 512 + lane * 8);
        for (int rb = 0; rb < 2; rb++)
          of[rb][nf] = __builtin_amdgcn_mfma_f32_16x16x32_bf16(pf[rb], vf, of[rb][nf], 0, 0, 0);
      }
    }
  }

  // normalize by the ones-column sums (d=72 -> nf=4, l16=8) and store
  for (int rb = 0; rb < 2; rb++) {
    float invl[4];
    for (int r = 0; r < 4; r++) {
      float lsum = __shfl(of[rb][4][r], (lane & 48) | 8);
      invl[r] = 1.0f / lsum;
    }
    for (int nf = 0; nf < 5; nf++) {
      int d = nf * 16 + l16;
      if (d < HDIM) {
        for (int r = 0; r < 4; r++) {
          size_t o = ((size_t)(b * 4096 + n0 + wid * 32 + rb * 16 + quad * 4 + r)) * DIMC +
                     h * HDIM + d;
          att[o] = f2bf(of[rb][nf][r] * invl[r]);
        }
      }
    }
  }
}

// ---------------------------------------------------------------------------
extern "C" void kernel_launch(void* const* d_in, const int* in_sizes, int n_in,
                              void* d_out, int out_size, void* d_ws, size_t ws_size,
                              hipStream_t stream) {
  const float* x      = (const float*)d_in[0];
  const float* cond   = (const float*)d_in[1];
  const int*   seqlen = (const int*)d_in[2];
  const float* q_w    = (const float*)d_in[3];
  const float* q_b    = (const float*)d_in[4];
  const float* kv_w   = (const float*)d_in[5];
  const float* kv_b   = (const float*)d_in[6];
  const float* proj_w = (const float*)d_in[7];
  const float* proj_b = (const float*)d_in[8];
  const float* qn_w   = (const float*)d_in[9];
  const float* kn_w   = (const float*)d_in[10];
  float* out = (float*)d_out;

  char* ws = (char*)d_ws;
  size_t o = 0;
  ushort_t* qwT    = (ushort_t*)(ws + o); o += (size_t)1152 * 1152 * 2;
  ushort_t* kvwT   = (ushort_t*)(ws + o); o += (size_t)2304 * 1152 * 2;
  ushort_t* pwT    = (ushort_t*)(ws + o); o += (size_t)1152 * 1152 * 2;
  ushort_t* q16    = (ushort_t*)(ws + o); o += (size_t)16384 * 1152 * 2;
  ushort_t* kv16   = (ushort_t*)(ws + o); o += (size_t)2048 * 2304 * 2;
  ushort_t* vT     = (ushort_t*)(ws + o); o += (size_t)64 * 80 * 512 * 2;
  ushort_t* att    = (ushort_t*)(ws + o); o += (size_t)16384 * 1152 * 2;
  ushort_t* x16    = (ushort_t*)(ws + o); o += (size_t)16384 * 1152 * 2;
  ushort_t* cond16 = (ushort_t*)(ws + o); o += (size_t)2048 * 1152 * 2;

  dim3 blk(256);

  // 0) activations fp32 -> bf16
  cvt_bf16_kernel<<<dim3((16384 * 1152 / 8 + 255) / 256), blk, 0, stream>>>(
      x, x16, 16384 * 1152 / 8);
  cvt_bf16_kernel<<<dim3((2048 * 1152 / 8 + 255) / 256), blk, 0, stream>>>(
      cond, cond16, 2048 * 1152 / 8);

  // 1) weight convert+transpose to bf16 [N][K]
  transpose_w_kernel<<<dim3(1152 / 64, 1152 / 64), blk, 0, stream>>>(q_w, qwT, 1152, 1152);
  transpose_w_kernel<<<dim3(1152 / 64, 2304 / 64), blk, 0, stream>>>(kv_w, kvwT, 1152, 2304);
  transpose_w_kernel<<<dim3(1152 / 64, 1152 / 64), blk, 0, stream>>>(proj_w, pwT, 1152, 1152);

  // 2+3) merged: Q = x @ q_w + q_b (1152 tiles) and KV = cond @ kv_w + kv_b
  //      (288 tiles) in one 1440-block dispatch (bf16 out)
  gemm128_kernel<false><<<dim3(1152 + 288), blk, 0, stream>>>(
      x16, qwT, q_b, q16, 9, 1152,
      cond16, kvwT, kv_b, kv16, 18, 2304,
      1152, 1152);

  // 4) RMSNorm k in place (pair-0 cols of kv16); q norm fused into attention
  rmsnorm_heads_kernel<<<dim3(2048 * 16 / 4), blk, 0, stream>>>(kv16, kn_w, 2304);

  // 5) V -> [b,h,d(80),m] with ones-row at d=72
  vtrans_kernel<<<dim3(64 * 80 / 4), blk, 0, stream>>>(kv16, vT);

  // 6) attention (fused Q-RMSNorm, no-max softmax)
  attn_kernel<<<dim3(32, 16, 4), blk, 0, stream>>>(q16, kv16, vT, seqlen, qn_w, att);

  // 7) out = att @ proj_w + proj_b  (fp32 out), 1152 blocks
  gemm128_kernel<true><<<dim3(1152), blk, 0, stream>>>(
      att, pwT, proj_b, out, 9, 1152,
      att, pwT, proj_b, out, 9, 1152,
      1152, 1152);
}

// Round 4
// 375.772 us; speedup vs baseline: 1.2679x; 1.0255x over previous
//
#include <hip/hip_runtime.h>
#include <math.h>

typedef unsigned short ushort_t;
typedef __attribute__((ext_vector_type(4))) float floatx4;
typedef __attribute__((ext_vector_type(8))) short bf16x8;

#define DIMC 1152
#define NHEADS 16
#define HDIM 72

__device__ __forceinline__ ushort_t f2bf(float f) {
  unsigned u = __float_as_uint(f);
  u += 0x7FFFu + ((u >> 16) & 1u);      // round-to-nearest-even
  return (ushort_t)(u >> 16);
}
__device__ __forceinline__ float bf2f(ushort_t s) {
  return __uint_as_float(((unsigned)s) << 16);
}

__device__ __forceinline__ void gload_lds16(const ushort_t* g, ushort_t* l) {
  __builtin_amdgcn_global_load_lds(
      (const __attribute__((address_space(1))) unsigned int*)(const void*)g,
      (__attribute__((address_space(3))) unsigned int*)(void*)l, 16, 0, 0);
}

__device__ __forceinline__ bf16x8 load_bf16x8(const ushort_t* p) {
  union { bf16x8 v; uint4 u; } t;
  t.u = *(const uint4*)p;
  return t.v;
}

// ---------------------------------------------------------------------------
// fp32 -> bf16 elementwise (8 elems/thread)
// ---------------------------------------------------------------------------
__global__ void cvt_bf16_kernel(const float* __restrict__ src,
                                ushort_t* __restrict__ dst, int n8) {
  int i = blockIdx.x * 256 + threadIdx.x;
  if (i >= n8) return;
  float4 f0 = ((const float4*)src)[2 * (size_t)i];
  float4 f1 = ((const float4*)src)[2 * (size_t)i + 1];
  union { ushort_t s[8]; uint4 u; } t;
  t.s[0] = f2bf(f0.x); t.s[1] = f2bf(f0.y); t.s[2] = f2bf(f0.z); t.s[3] = f2bf(f0.w);
  t.s[4] = f2bf(f1.x); t.s[5] = f2bf(f1.y); t.s[6] = f2bf(f1.z); t.s[7] = f2bf(f1.w);
  ((uint4*)dst)[i] = t.u;
}

// ---------------------------------------------------------------------------
// W [K][N] fp32  ->  Wt [N][K] bf16   (64x64 tiles via LDS)
// ---------------------------------------------------------------------------
__global__ void transpose_w_kernel(const float* __restrict__ W,
                                   ushort_t* __restrict__ Wt, int K, int N) {
  __shared__ ushort_t tile[64 * 80];
  int k0 = blockIdx.x * 64, n0 = blockIdx.y * 64;
  int tid = threadIdx.x;
  int kl = tid >> 4, n4 = tid & 15;
  for (int rr = 0; rr < 4; rr++) {
    int k = kl + rr * 16;
    float4 f = *(const float4*)(W + (size_t)(k0 + k) * N + n0 + n4 * 4);
    tile[(n4 * 4 + 0) * 80 + k] = f2bf(f.x);
    tile[(n4 * 4 + 1) * 80 + k] = f2bf(f.y);
    tile[(n4 * 4 + 2) * 80 + k] = f2bf(f.z);
    tile[(n4 * 4 + 3) * 80 + k] = f2bf(f.w);
  }
  __syncthreads();
  int nl = tid >> 2, kq = tid & 3;
  uint4 v0 = *(const uint4*)(tile + nl * 80 + kq * 16);
  uint4 v1 = *(const uint4*)(tile + nl * 80 + kq * 16 + 8);
  *(uint4*)(Wt + (size_t)(n0 + nl) * K + k0 + kq * 16) = v0;
  *(uint4*)(Wt + (size_t)(n0 + nl) * K + k0 + kq * 16 + 8) = v1;
}

// ---------------------------------------------------------------------------
// 128x128 fine-grained 2-phase GEMM, BK=32, 256 threads (4 waves 2x2,
// per-wave 64x64 = acc[4][4]). LDS 48 KiB = 3 bufs x (A 8K + B 8K)
// -> 3 blocks/CU co-resident.
// 3-deep rotation: during tile t, stage BOTH A(t+2) and B(t+2) into
// buffer (t+2)%3 (free since tile t-1 retired at its trailing barrier).
// End-of-tile guard vmcnt(4) waits for tile (t+1)'s 4 loads, which were
// issued a FULL TILE earlier -> slack > HBM latency, stall eliminated
// (round-2's 2-buffer scheme gave A only ~1.5 phases of slack).
// XOR swizzle: src pre-swizzled for global_load_lds linear dst; reads
// apply the same XOR -> conflict-free ds_read_b128.
// Two independent problem segments routed by block id (merges the Q and
// KV projections into one dispatch). Grid must be %8 == 0 for XCD swizzle.
// ---------------------------------------------------------------------------
template <bool OUT_F32>
__global__ __launch_bounds__(256, 3) void gemm128_kernel(
    const ushort_t* __restrict__ A0, const ushort_t* __restrict__ Bt0,
    const float* __restrict__ bias0, void* __restrict__ C0,
    int NTn0, int Ncols0,
    const ushort_t* __restrict__ A1, const ushort_t* __restrict__ Bt1,
    const float* __restrict__ bias1, void* __restrict__ C1,
    int NTn1, int Ncols1,
    int nblk0, int Kdim) {
  __shared__ ushort_t S[24576];  // 48 KiB: buf*8192 + {A:0, B:4096}

  int lin = blockIdx.x;
  int cpx = gridDim.x >> 3;
  int wg = (lin & 7) * cpx + (lin >> 3);   // XCD-contiguous chunks

  const ushort_t* Aseg; const ushort_t* Bseg;
  const float* bias; void* Cptr; int NTn, Ncols;
  if (wg < nblk0) {
    Aseg = A0; Bseg = Bt0; bias = bias0; Cptr = C0; NTn = NTn0; Ncols = Ncols0;
  } else {
    wg -= nblk0;
    Aseg = A1; Bseg = Bt1; bias = bias1; Cptr = C1; NTn = NTn1; Ncols = Ncols1;
  }
  int mt = wg / NTn, nt = wg % NTn;
  int m0 = mt * 128, n0 = nt * 128;

  int tid = threadIdx.x;
  int wid = tid >> 6, lane = tid & 63, quad = lane >> 4, l16 = lane & 15;
  int wr = wid >> 1, wc = wid & 1;
  const int qoff = (quad * 8) ^ ((l16 & 8) << 1);  // swizzled read col (ushorts)

  // staging source coords (per thread), pre-swizzled; one call = 64 rows x 32k
  const int srow = tid >> 2;                                   // 0..63
  const int scol = ((tid & 3) * 8) ^ ((tid & 32) ? 16 : 0);    // ushorts
  const ushort_t* Abase = Aseg + (size_t)m0 * Kdim;
  const ushort_t* Bbase = Bseg + (size_t)n0 * Kdim;

  auto stageA = [&](int t, int buf) {
    const ushort_t* src = Abase + (size_t)srow * Kdim + t * 32 + scol;
    ushort_t* dst = S + buf * 8192 + (tid >> 6) * 512;
    gload_lds16(src, dst);                             // rows 0..63
    gload_lds16(src + (size_t)64 * Kdim, dst + 2048);  // rows 64..127
  };
  auto stageB = [&](int t, int buf) {
    const ushort_t* src = Bbase + (size_t)srow * Kdim + t * 32 + scol;
    ushort_t* dst = S + buf * 8192 + 4096 + (tid >> 6) * 512;
    gload_lds16(src, dst);
    gload_lds16(src + (size_t)64 * Kdim, dst + 2048);
  };

  floatx4 zero = {0.f, 0.f, 0.f, 0.f};
  floatx4 acc[4][4];
#pragma unroll
  for (int i = 0; i < 4; i++)
#pragma unroll
    for (int j = 0; j < 4; j++) acc[i][j] = zero;

  int NT = Kdim >> 5;   // K-tiles of 32

  // prologue: tiles 0 and 1 fully staged; guard tile 0 complete
  stageA(0, 0); stageB(0, 0);
  stageA(1, 1); stageB(1, 1);
  asm volatile("s_waitcnt vmcnt(4)" ::: "memory");
  __builtin_amdgcn_s_barrier();

  int cur = 0;
  for (int t = 0; t < NT; ++t) {
    int nx2 = cur + 2; if (nx2 >= 3) nx2 -= 3;
    const int base = cur * 8192;
    const int arow = base + (wr * 64 + l16) * 32 + qoff;
    const int brow = base + 4096 + (wc * 64 + l16) * 32 + qoff;

    // ---------------- phase 0 : B all + A frags 0,1 ----------------
    bf16x8 bfr[4], a01[2];
#pragma unroll
    for (int c = 0; c < 4; c++)
      bfr[c] = *(const bf16x8*)(S + brow + c * 512);
    a01[0] = *(const bf16x8*)(S + arow);
    a01[1] = *(const bf16x8*)(S + arow + 512);
    if (t + 2 < NT) stageA(t + 2, nx2);
    __builtin_amdgcn_s_barrier();
    asm volatile("s_waitcnt lgkmcnt(0)" ::: "memory");
    __builtin_amdgcn_sched_barrier(0);
    __builtin_amdgcn_s_setprio(1);
#pragma unroll
    for (int c = 0; c < 4; c++) {
      acc[0][c] = __builtin_amdgcn_mfma_f32_16x16x32_bf16(a01[0], bfr[c], acc[0][c], 0, 0, 0);
      acc[1][c] = __builtin_amdgcn_mfma_f32_16x16x32_bf16(a01[1], bfr[c], acc[1][c], 0, 0, 0);
    }
    __builtin_amdgcn_s_setprio(0);
    __builtin_amdgcn_s_barrier();

    // ---------------- phase 1 : A frags 2,3 ----------------
    bf16x8 a23[2];
    a23[0] = *(const bf16x8*)(S + arow + 1024);
    a23[1] = *(const bf16x8*)(S + arow + 1536);
    if (t + 2 < NT) stageB(t + 2, nx2);
    __builtin_amdgcn_s_barrier();
    asm volatile("s_waitcnt lgkmcnt(0)" ::: "memory");
    __builtin_amdgcn_sched_barrier(0);
    __builtin_amdgcn_s_setprio(1);
#pragma unroll
    for (int c = 0; c < 4; c++) {
      acc[2][c] = __builtin_amdgcn_mfma_f32_16x16x32_bf16(a23[0], bfr[c], acc[2][c], 0, 0, 0);
      acc[3][c] = __builtin_amdgcn_mfma_f32_16x16x32_bf16(a23[1], bfr[c], acc[3][c], 0, 0, 0);
    }
    __builtin_amdgcn_s_setprio(0);
    // guard: tile (t+1) must be resident; its loads were issued at tile t-1.
    if (t + 2 < NT)
      asm volatile("s_waitcnt vmcnt(4)" ::: "memory");
    else
      asm volatile("s_waitcnt vmcnt(0)" ::: "memory");
    __builtin_amdgcn_s_barrier();

    cur = cur + 1; if (cur == 3) cur = 0;
  }

  // epilogue
  float bv[4];
#pragma unroll
  for (int c = 0; c < 4; c++) bv[c] = bias[n0 + wc * 64 + c * 16 + l16];
#pragma unroll
  for (int mf = 0; mf < 4; mf++)
#pragma unroll
    for (int c = 0; c < 4; c++)
#pragma unroll
      for (int r = 0; r < 4; r++) {
        int row = m0 + wr * 64 + mf * 16 + quad * 4 + r;
        int col = n0 + wc * 64 + c * 16 + l16;
        float v = acc[mf][c][r] + bv[c];
        if constexpr (OUT_F32)
          ((float*)Cptr)[(size_t)row * Ncols + col] = v;
        else
          ((ushort_t*)Cptr)[(size_t)row * Ncols + col] = f2bf(v);
      }
}

// ---------------------------------------------------------------------------
// In-place per-head RMSNorm on bf16 (one wave per (row, head); 72 elems).
// Used only for K (Q norm fused into attention).
// ---------------------------------------------------------------------------
__global__ void rmsnorm_heads_kernel(ushort_t* __restrict__ p,
                                     const float* __restrict__ w,
                                     int rowstride) {
  int gw = blockIdx.x * 4 + (threadIdx.x >> 6);
  int lane = threadIdx.x & 63;
  int row = gw >> 4, h = gw & 15;
  ushort_t* base = p + (size_t)row * rowstride + h * HDIM;
  float v0 = bf2f(base[lane]);
  float v1 = (lane < 8) ? bf2f(base[64 + lane]) : 0.f;
  float ss = v0 * v0 + v1 * v1;
  for (int off = 1; off < 64; off <<= 1) ss += __shfl_xor(ss, off);
  float inv = rsqrtf(ss / 72.0f + 1e-6f);
  base[lane] = f2bf(v0 * inv * w[lane]);
  if (lane < 8) base[64 + lane] = f2bf(v1 * inv * w[64 + lane]);
}

// ---------------------------------------------------------------------------
// V [b,m,pair1,h,d] -> vT [b,h,d(80),m(512)] via LDS-tiled transpose.
// Coalesced 8-B global loads (rows of the head-slice), padded-stride LDS
// (84 ushorts), coalesced 8-B stores.
// d==72 row = ONES (gives P row-sums for free via the PV MFMA),
// d in (72,80) zeros. Grid (8 mchunks, 16 h, 4 b), 256 threads.
// ---------------------------------------------------------------------------
__global__ void vtrans_kernel(const ushort_t* __restrict__ kv16,
                              ushort_t* __restrict__ vT) {
  __shared__ ushort_t tile[64 * 84];
  int b = blockIdx.z, h = blockIdx.y, m0 = blockIdx.x * 64;
  int tid = threadIdx.x;
  int row = tid >> 2, sl = tid & 3;
  const ushort_t* src =
      kv16 + (size_t)(b * 512 + m0 + row) * 2304 + DIMC + h * HDIM;
#pragma unroll
  for (int k = 0; k < 5; k++) {
    int s = sl + 4 * k;            // segments of 4 ushorts; 18 segs = 72 elems
    if (s < 18) {
      uint2 v = *(const uint2*)(src + s * 4);
      *(uint2*)(tile + row * 84 + s * 4) = v;
    }
  }
  __syncthreads();
  size_t dbase = (size_t)((b * 16 + h) * 80) * 512 + m0;
#pragma unroll
  for (int it = 0; it < 5; it++) {
    int idx = it * 256 + tid;      // 1280 = 80 d-rows x 16 msegs, exact
    int d = idx >> 4, mseg = idx & 15;
    union { ushort_t s[4]; uint2 u; } pk;
    if (d < HDIM) {
      pk.s[0] = tile[(mseg * 4 + 0) * 84 + d];
      pk.s[1] = tile[(mseg * 4 + 1) * 84 + d];
      pk.s[2] = tile[(mseg * 4 + 2) * 84 + d];
      pk.s[3] = tile[(mseg * 4 + 3) * 84 + d];
    } else {
      ushort_t f = (d == HDIM) ? (ushort_t)0x3F80 : (ushort_t)0;  // 1.0 or 0
      pk.s[0] = pk.s[1] = pk.s[2] = pk.s[3] = f;
    }
    *(uint2*)(vT + dbase + (size_t)d * 512 + mseg * 4) = pk.u;
  }
}

// ---------------------------------------------------------------------------
// Flash cross-attention, fused Q-RMSNorm, no-max softmax (post-RMSNorm
// |s*scale| <= sqrt(72) ~ 8.5, exp2-safe in fp32). K/V tiles staged
// cooperatively into LDS via global_load_lds width 16 in MFMA-fragment
// chunk order: 22 chunks x 1KB, waves stage 6/6/5/5, 2 barriers per tile;
// all LDS accesses are conflict-free b128.
// P row-sums via ones-row (d=72) of vT through the PV MFMA.
// Ps is wave-private, XOR-swizzled.
// ---------------------------------------------------------------------------
__global__ __launch_bounds__(256, 4) void attn_kernel(
    const ushort_t* __restrict__ q16, const ushort_t* __restrict__ kv16,
    const ushort_t* __restrict__ vT, const int* __restrict__ seqlens,
    const float* __restrict__ qn_w, ushort_t* __restrict__ att) {
  __shared__ ushort_t KV[22 * 512];     // K chunks 0..11 (c*3+ks), V 12..21 (12+nf*2+ks)
  __shared__ ushort_t Ps[4][32 * 64];   // per-wave [row 32][m 64] swizzled
  int b = blockIdx.z, h = blockIdx.y, n0 = blockIdx.x * 128;
  int tid = threadIdx.x, wid = tid >> 6, lane = tid & 63;
  int quad = lane >> 4, l16 = lane & 15;
  int seqlen = seqlens[b];
  // 1/sqrt(72) * log2(e) folded into Q so that P = exp2(S)
  const float qscale = 0.11785113019775793f * 1.44269504088896f;

  ushort_t* Pw = &Ps[wid][0];

  // --- Q fragments + fused RMSNorm (qn_w and qscale folded in) ---
  bf16x8 qf[2][3];
  float ssq[2] = {0.f, 0.f};
  for (int rb = 0; rb < 2; rb++)
    for (int ks = 0; ks < 3; ks++) {
      if (ks == 2 && quad > 0) {
        qf[rb][ks] = (bf16x8){0, 0, 0, 0, 0, 0, 0, 0};
      } else {
        size_t off = ((size_t)(b * 4096 + n0 + wid * 32 + rb * 16 + l16)) * DIMC +
                     h * HDIM + ks * 32 + quad * 8;
        qf[rb][ks] = load_bf16x8(q16 + off);
        union { bf16x8 v; ushort_t s[8]; } e;
        e.v = qf[rb][ks];
        for (int j = 0; j < 8; j++) {
          float x = bf2f(e.s[j]);
          ssq[rb] += x * x;
        }
      }
    }
  for (int rb = 0; rb < 2; rb++) {
    ssq[rb] += __shfl_xor(ssq[rb], 16);
    ssq[rb] += __shfl_xor(ssq[rb], 32);
  }
  for (int rb = 0; rb < 2; rb++) {
    float inv = rsqrtf(ssq[rb] / 72.0f + 1e-6f) * qscale;
    for (int ks = 0; ks < 3; ks++) {
      if (ks == 2 && quad > 0) continue;
      float4 w0 = *(const float4*)(qn_w + ks * 32 + quad * 8);
      float4 w1 = *(const float4*)(qn_w + ks * 32 + quad * 8 + 4);
      union { bf16x8 v; ushort_t s[8]; } e;
      e.v = qf[rb][ks];
      e.s[0] = f2bf(bf2f(e.s[0]) * inv * w0.x);
      e.s[1] = f2bf(bf2f(e.s[1]) * inv * w0.y);
      e.s[2] = f2bf(bf2f(e.s[2]) * inv * w0.z);
      e.s[3] = f2bf(bf2f(e.s[3]) * inv * w0.w);
      e.s[4] = f2bf(bf2f(e.s[4]) * inv * w1.x);
      e.s[5] = f2bf(bf2f(e.s[5]) * inv * w1.y);
      e.s[6] = f2bf(bf2f(e.s[6]) * inv * w1.z);
      e.s[7] = f2bf(bf2f(e.s[7]) * inv * w1.w);
      qf[rb][ks] = e.v;
    }
  }

  floatx4 zero = {0.f, 0.f, 0.f, 0.f};
  floatx4 of[2][5];
  for (int rb = 0; rb < 2; rb++)
    for (int nf = 0; nf < 5; nf++) of[rb][nf] = zero;

  const size_t kvrow = (size_t)b * 512;
  const size_t vbase = (size_t)((b * 16 + h) * 80) * 512;

  int ntiles = (seqlen + 63) >> 6;
  for (int mt = 0; mt < ntiles; mt++) {
    int m0 = mt * 64;

    __syncthreads();   // previous tile's LDS reads done
    // cooperative staging: 22 chunks, wave w takes id = w, w+4, ...
    for (int id = wid; id < 22; id += 4) {
      const ushort_t* src;
      if (id < 12) {
        int c = (id * 11) >> 5;     // floor(id/3) for id<12: 0..3
        int ks = id - c * 3;
        src = kv16 + (size_t)(kvrow + m0 + c * 16 + l16) * 2304 + h * HDIM +
              ks * 32 + quad * 8;
      } else {
        int v = id - 12;
        int nf = v >> 1, ks = v & 1;
        src = vT + (vbase + (size_t)(nf * 16 + l16) * 512) + m0 + ks * 32 + quad * 8;
      }
      gload_lds16(src, KV + id * 512);
    }
    __syncthreads();   // staging complete

    // S = Q K^T from LDS K-frags (d >= 72 garbage x Q-zeros)
    floatx4 sf[2][4];
    for (int rb = 0; rb < 2; rb++)
      for (int c = 0; c < 4; c++) sf[rb][c] = zero;
    for (int c = 0; c < 4; c++)
      for (int ks = 0; ks < 3; ks++) {
        bf16x8 kf = *(const bf16x8*)(KV + (c * 3 + ks) * 512 + lane * 8);
        for (int rb = 0; rb < 2; rb++)
          sf[rb][c] = __builtin_amdgcn_mfma_f32_16x16x32_bf16(qf[rb][ks], kf, sf[rb][c], 0, 0, 0);
      }

    // P = exp2(S) masked; write to wave-private swizzled LDS
    for (int rb = 0; rb < 2; rb++)
      for (int c = 0; c < 4; c++) {
        bool valid = (m0 + c * 16 + l16) < seqlen;
        int col = (c * 16 + l16) ^ (quad * 16);
        int rowb = rb * 16 + quad * 4;
        for (int r = 0; r < 4; r++) {
          float pp = valid ? __builtin_amdgcn_exp2f(sf[rb][c][r]) : 0.f;
          Pw[(rowb + r) * 64 + col] = f2bf(pp);
        }
      }

    // O += P V from LDS V-frags (nf=4 includes ones-row d=72)
    for (int ks = 0; ks < 2; ks++) {
      bf16x8 pf[2];
      int g = ((ks * 2 + (quad >> 1)) * 16 + (quad & 1) * 8) ^ (((l16 >> 2) & 3) * 16);
      for (int rb = 0; rb < 2; rb++)
        pf[rb] = *(const bf16x8*)(Pw + (rb * 16 + l16) * 64 + g);
      for (int nf = 0; nf < 5; nf++) {
        bf16x8 vf = *(const bf16x8*)(KV + (12 + nf * 2 + ks) * 512 + lane * 8);
        for (int rb = 0; rb < 2; rb++)
          of[rb][nf] = __builtin_amdgcn_mfma_f32_16x16x32_bf16(pf[rb], vf, of[rb][nf], 0, 0, 0);
      }
    }
  }

  // normalize by the ones-column sums (d=72 -> nf=4, l16=8) and store
  for (int rb = 0; rb < 2; rb++) {
    float invl[4];
    for (int r = 0; r < 4; r++) {
      float lsum = __shfl(of[rb][4][r], (lane & 48) | 8);
      invl[r] = 1.0f / lsum;
    }
    for (int nf = 0; nf < 5; nf++) {
      int d = nf * 16 + l16;
      if (d < HDIM) {
        for (int r = 0; r < 4; r++) {
          size_t o = ((size_t)(b * 4096 + n0 + wid * 32 + rb * 16 + quad * 4 + r)) * DIMC +
                     h * HDIM + d;
          att[o] = f2bf(of[rb][nf][r] * invl[r]);
        }
      }
    }
  }
}

// ---------------------------------------------------------------------------
extern "C" void kernel_launch(void* const* d_in, const int* in_sizes, int n_in,
                              void* d_out, int out_size, void* d_ws, size_t ws_size,
                              hipStream_t stream) {
  const float* x      = (const float*)d_in[0];
  const float* cond   = (const float*)d_in[1];
  const int*   seqlen = (const int*)d_in[2];
  const float* q_w    = (const float*)d_in[3];
  const float* q_b    = (const float*)d_in[4];
  const float* kv_w   = (const float*)d_in[5];
  const float* kv_b   = (const float*)d_in[6];
  const float* proj_w = (const float*)d_in[7];
  const float* proj_b = (const float*)d_in[8];
  const float* qn_w   = (const float*)d_in[9];
  const float* kn_w   = (const float*)d_in[10];
  float* out = (float*)d_out;

  char* ws = (char*)d_ws;
  size_t o = 0;
  ushort_t* qwT    = (ushort_t*)(ws + o); o += (size_t)1152 * 1152 * 2;
  ushort_t* kvwT   = (ushort_t*)(ws + o); o += (size_t)2304 * 1152 * 2;
  ushort_t* pwT    = (ushort_t*)(ws + o); o += (size_t)1152 * 1152 * 2;
  ushort_t* q16    = (ushort_t*)(ws + o); o += (size_t)16384 * 1152 * 2;
  ushort_t* kv16   = (ushort_t*)(ws + o); o += (size_t)2048 * 2304 * 2;
  ushort_t* vT     = (ushort_t*)(ws + o); o += (size_t)64 * 80 * 512 * 2;
  ushort_t* att    = (ushort_t*)(ws + o); o += (size_t)16384 * 1152 * 2;
  ushort_t* x16    = (ushort_t*)(ws + o); o += (size_t)16384 * 1152 * 2;
  ushort_t* cond16 = (ushort_t*)(ws + o); o += (size_t)2048 * 1152 * 2;

  dim3 blk(256);

  // 0) activations fp32 -> bf16
  cvt_bf16_kernel<<<dim3((16384 * 1152 / 8 + 255) / 256), blk, 0, stream>>>(
      x, x16, 16384 * 1152 / 8);
  cvt_bf16_kernel<<<dim3((2048 * 1152 / 8 + 255) / 256), blk, 0, stream>>>(
      cond, cond16, 2048 * 1152 / 8);

  // 1) weight convert+transpose to bf16 [N][K]
  transpose_w_kernel<<<dim3(1152 / 64, 1152 / 64), blk, 0, stream>>>(q_w, qwT, 1152, 1152);
  transpose_w_kernel<<<dim3(1152 / 64, 2304 / 64), blk, 0, stream>>>(kv_w, kvwT, 1152, 2304);
  transpose_w_kernel<<<dim3(1152 / 64, 1152 / 64), blk, 0, stream>>>(proj_w, pwT, 1152, 1152);

  // 2+3) merged: Q = x @ q_w + q_b (1152 tiles) and KV = cond @ kv_w + kv_b
  //      (288 tiles) in one 1440-block dispatch (bf16 out)
  gemm128_kernel<false><<<dim3(1152 + 288), blk, 0, stream>>>(
      x16, qwT, q_b, q16, 9, 1152,
      cond16, kvwT, kv_b, kv16, 18, 2304,
      1152, 1152);

  // 4) RMSNorm k in place (pair-0 cols of kv16); q norm fused into attention
  rmsnorm_heads_kernel<<<dim3(2048 * 16 / 4), blk, 0, stream>>>(kv16, kn_w, 2304);

  // 5) V -> [b,h,d(80),m] with ones-row at d=72 (LDS-tiled, coalesced)
  vtrans_kernel<<<dim3(8, 16, 4), blk, 0, stream>>>(kv16, vT);

  // 6) attention (fused Q-RMSNorm, no-max softmax)
  attn_kernel<<<dim3(32, 16, 4), blk, 0, stream>>>(q16, kv16, vT, seqlen, qn_w, att);

  // 7) out = att @ proj_w + proj_b  (fp32 out), 1152 blocks
  gemm128_kernel<true><<<dim3(1152), blk, 0, stream>>>(
      att, pwT, proj_b, out, 9, 1152,
      att, pwT, proj_b, out, 9, 1152,
      1152, 1152);
}